// Round 6
// baseline (589.601 us; speedup 1.0000x reference)
//
#include <hip/hip_runtime.h>

// Problem constants
#define BB   4
#define CC   256
#define NPIX 4096            // 64*64
#define PB   1048576         // per-batch elements: NPIX*CC
#define NTOT 16384           // B * NPIX (batch folded into GEMM N)

typedef __attribute__((ext_vector_type(8))) short bf16x8;
typedef __attribute__((ext_vector_type(4))) float f32x4;
typedef __attribute__((ext_vector_type(4))) unsigned short u16x4;

__device__ __forceinline__ unsigned short f2b(float f) {
  union { float f; unsigned u; } v; v.f = f;
  unsigned r = v.u + 0x7fffu + ((v.u >> 16) & 1u);
  return (unsigned short)(r >> 16);
}
__device__ __forceinline__ float b2f(unsigned short h) {
  union { unsigned u; float f; } v; v.u = ((unsigned)h) << 16;
  return v.f;
}
__device__ __forceinline__ f32x4 mfma16(bf16x8 a, bf16x8 b, f32x4 c) {
  return __builtin_amdgcn_mfma_f32_16x16x32_bf16(a, b, c, 0, 0, 0);
}
// async global->LDS, 16B per lane. LDS dst = wave-uniform base + lane*16 (linear).
__device__ __forceinline__ void gload_lds16(const unsigned short* g, unsigned short* l) {
  __builtin_amdgcn_global_load_lds(
      (const __attribute__((address_space(1))) unsigned int*)g,
      (__attribute__((address_space(3))) unsigned int*)l, 16, 0, 0);
}
// reflect-pad(1) pixel remap for 64x64 image
__device__ __forceinline__ int remap_px(int n, int dh, int dw) {
  int h = (n >> 6) + dh;
  int w = (n & 63) + dw;
  h = h < 0 ? 1 : (h > 63 ? 62 : h);
  w = w < 0 ? 1 : (w > 63 ? 62 : w);
  return (h << 6) | w;
}

// ---------------- weight / bias repack ----------------
__global__ void repack_w1x1_k(const float* __restrict__ tw, const float* __restrict__ pw,
                              const float* __restrict__ gw, const float* __restrict__ Ww,
                              unsigned short* __restrict__ dst) {
  int i = blockIdx.x * 256 + threadIdx.x;          // 65536 total
  dst[i]           = f2b(tw[i]);
  dst[65536 + i]   = f2b(pw[i]);
  dst[131072 + i]  = f2b(gw[i]);
  dst[196608 + i]  = f2b(Ww[i]);
}

__global__ void repack_bias_k(const float* __restrict__ tb, const float* __restrict__ pb,
                              const float* __restrict__ gb, const float* __restrict__ Wb,
                              float* __restrict__ bias) {
  int i = blockIdx.x * 256 + threadIdx.x;          // 1024
  float v;
  if (i < 256) v = tb[i];
  else if (i < 512) v = pb[i - 256];
  else if (i < 768) v = gb[i - 512];
  else v = Wb[i - 768];
  bias[i] = v;
}

__global__ void repack_res_k(const float* __restrict__ w1, const float* __restrict__ w2,
                             unsigned short* __restrict__ wk) {
  int idx = blockIdx.x * 256 + threadIdx.x;        // 3*256*256*9 = 1769472 total
  if (idx >= 1769472) return;
  int t = idx % 9;
  int rest = idx / 9;                              // (i*256+o)*256+c
  int c = rest & 255;
  int o = (rest >> 8) & 255;
  int i = rest >> 16;
  size_t d = (size_t)t * 65536 + o * 256 + c;      // [t][o][c] within one conv
  wk[(size_t)(2 * i)     * 589824 + d] = f2b(w1[idx]);
  wk[(size_t)(2 * i + 1) * 589824 + d] = f2b(w2[idx]);
}

// ---------------- mask prep ----------------
__global__ void prep_mask_k(const float* __restrict__ mask, float* __restrict__ m) {
  int idx = blockIdx.x * 256 + threadIdx.x;        // B*4096
  if (idx >= BB * NPIX) return;
  int b = idx >> 12, n = idx & 4095;
  int h = n >> 6, w = n & 63;
  const float* M = mask + b * 1024;
  float sh = 0.5f * h - 0.25f, sw = 0.5f * w - 0.25f;
  int h0 = (int)floorf(sh), w0 = (int)floorf(sw);
  float th = sh - h0, tw = sw - w0;
  int h0c = min(max(h0, 0), 31), h1c = min(max(h0 + 1, 0), 31);
  int w0c = min(max(w0, 0), 31), w1c = min(max(w0 + 1, 0), 31);
  float v = (1.f - th) * ((1.f - tw) * M[h0c * 32 + w0c] + tw * M[h0c * 32 + w1c])
          +        th  * ((1.f - tw) * M[h1c * 32 + w0c] + tw * M[h1c * 32 + w1c]);
  float inv = v > 0.f ? 0.f : 1.f;
  float tmp = 1.f - M[(h >> 1) * 32 + (w >> 1)];
  m[idx] = inv * tmp;                              // binary {0,1}
}

// ---------------- key compaction: scan + gathers ----------------
__global__ void mask_scan_k(const float* __restrict__ mbuf, int* __restrict__ ci,
                            int* __restrict__ kcount) {
  int b = blockIdx.x;
  int tid = threadIdx.x;                           // 256, 16 pix each
  __shared__ int sc[256];
  const float* mb = mbuf + b * 4096;
  int n0 = tid * 16, cnt = 0;
  float mv[16];
  #pragma unroll
  for (int i = 0; i < 16; ++i) { mv[i] = mb[n0 + i]; cnt += mv[i] > 0.f ? 1 : 0; }
  sc[tid] = cnt;
  __syncthreads();
  for (int off = 1; off < 256; off <<= 1) {
    int v = sc[tid];
    int u = tid >= off ? sc[tid - off] : 0;
    __syncthreads();
    sc[tid] = v + u;
    __syncthreads();
  }
  int base = sc[tid] - cnt;                        // exclusive prefix
  int* cib = ci + b * 4096;
  #pragma unroll
  for (int i = 0; i < 16; ++i)
    if (mv[i] > 0.f) cib[base++] = n0 + i;
  if (tid == 255) kcount[b] = sc[255];
}

__global__ void gather_phi_k(const unsigned short* __restrict__ phb, const int* __restrict__ ci,
                             const int* __restrict__ kcount, unsigned short* __restrict__ phic) {
  int b = blockIdx.y;
  int Kb = kcount[b];
  int pad = (Kb + 63) & ~63;
  int j = blockIdx.x * 8 + (threadIdx.x >> 5);
  int cl = threadIdx.x & 31;
  if (j >= pad) return;
  bf16x8 v;
  if (j < Kb) {
    v = *(const bf16x8*)(phb + (size_t)b * PB + (size_t)ci[b * 4096 + j] * 256 + cl * 8);
  } else {
    for (int t = 0; t < 8; ++t) v[t] = 0;
  }
  *(bf16x8*)(phic + (size_t)b * PB + (size_t)j * 256 + cl * 8) = v;
}

__global__ void gather_g_k(const unsigned short* __restrict__ gbuf, const int* __restrict__ ci,
                           const int* __restrict__ kcount, unsigned short* __restrict__ gc) {
  int b = blockIdx.z;
  int Kb = kcount[b];
  int pad = (Kb + 63) & ~63;
  int c = blockIdx.y;
  int j = blockIdx.x * 256 + threadIdx.x;
  if (j >= pad) return;
  unsigned short v = 0;
  if (j < Kb) v = gbuf[(size_t)c * NTOT + b * 4096 + ci[b * 4096 + j]];
  gc[(size_t)c * NTOT + b * 4096 + j] = v;
}

// ---------------- x transpose: [B,C,N] f32 -> [B,N,C] bf16 ----------------
__global__ void transpose_x_k(const float* __restrict__ x, unsigned short* __restrict__ xT) {
  __shared__ float T[64][65];
  int b = blockIdx.z;
  int n0 = blockIdx.x * 64, c0 = blockIdx.y * 64;
  int tx = threadIdx.x, ty = threadIdx.y;
  const float* xb = x + (size_t)b * PB;
  #pragma unroll
  for (int i = 0; i < 16; ++i) {
    int cl = ty + i * 4;
    T[cl][tx] = xb[(size_t)(c0 + cl) * NPIX + n0 + tx];
  }
  __syncthreads();
  unsigned short* ob = xT + (size_t)b * PB;
  #pragma unroll
  for (int i = 0; i < 16; ++i) {
    int nl = ty + i * 4;
    ob[(size_t)(n0 + nl) * CC + c0 + tx] = f2b(T[tx][nl]);
  }
}

// ---------------- weight-stationary GEMM: C[M,NTOT] = A[M,K] * Bact[NTOT,K]^T ----------------
// v2: TM=128, TN=64, BK=64, 128 threads (2 waves), per-wave 64x64 output tile.
// Both operands LDS-staged via global_load_lds (XOR-swizzled), DOUBLE-buffered with
// stage-ahead (m97 pattern): one barrier per K-step, next tile's loads fly under MFMA.
// Per wave per kk: 4 A + 4 B ds_read_b128 feed 16 MFMA (32 FLOP/LDS-byte -> MFMA-bound).
// EPI 0: fused theta|phi|g (M=768); EPI 1: bf16 [B,N,C]; EPI 2: f32+bf16 (+bias)
template <int EPI, int TAPS>
__launch_bounds__(128, 2)
__global__ void gemm_w(const unsigned short* __restrict__ A,
                       const unsigned short* __restrict__ Bact,
                       const float* __restrict__ bias,
                       float* __restrict__ outF,
                       unsigned short* __restrict__ o0,
                       unsigned short* __restrict__ o1,
                       unsigned short* __restrict__ o2) {
  int m0 = blockIdx.y * 128;
  int bxs = (blockIdx.x & 7) * 32 + (blockIdx.x >> 3);   // XCD-chunked n-tiles (256 = 8x32)
  int n0 = bxs * 64;
  int tid = threadIdx.x, lane = tid & 63, wid = tid >> 6;  // 2 waves
  int r16 = lane & 15, g4 = lane >> 4;
  __shared__ __align__(16) unsigned short As[2 * 8192];   // 2 x 128 rows x 128B
  __shared__ __align__(16) unsigned short Bs[2 * 4096];   // 2 x  64 rows x 128B
  f32x4 acc[4][4] = {};
  // staging geometry: issue q covers LDS bytes L = tid*16 + q*2048 (A: q 0..7, B: q 0..3)
  int sr[8], sc[8];
  #pragma unroll
  for (int q = 0; q < 8; ++q) {
    sr[q] = (tid >> 3) + q * 16;
    sc[q] = (((tid * 16) & 127) ^ ((sr[q] & 7) << 4)) >> 1;  // pre-swizzled global col (elems)
  }
  // LDS read bases (bytes); xor chunk uses q7 = r16&7 (rows are 16-aligned per fragment)
  int q7 = r16 & 7;
  int ra[4], rbv[4];
  #pragma unroll
  for (int i = 0; i < 4; ++i) ra[i] = (wid * 64 + i * 16 + r16) * 128;
  #pragma unroll
  for (int j = 0; j < 4; ++j) rbv[j] = (j * 16 + r16) * 128;

  const int nsteps = TAPS * 4;

#define STAGE(st_, bs_) do {                                                      \
    int tap_ = (st_) >> 2, k0_ = ((st_) & 3) * 64;                                \
    const unsigned short* At_ = A + tap_ * 65536;                                 \
    _Pragma("unroll")                                                             \
    for (int q = 0; q < 8; ++q)                                                   \
      gload_lds16(At_ + (size_t)(m0 + sr[q]) * 256 + k0_ + sc[q],                 \
                  &As[(bs_) * 8192 + tid * 8 + q * 1024]);                        \
    _Pragma("unroll")                                                             \
    for (int q = 0; q < 4; ++q) {                                                 \
      int n_ = n0 + sr[q];                                                        \
      int bsrc_ = n_;                                                             \
      if (TAPS == 9) bsrc_ = (n_ & ~4095) | remap_px(n_ & 4095, tap_ / 3 - 1, tap_ % 3 - 1); \
      gload_lds16(Bact + (size_t)bsrc_ * 256 + k0_ + sc[q],                       \
                  &Bs[(bs_) * 4096 + tid * 8 + q * 1024]);                        \
    }                                                                             \
  } while (0)

#define COMPUTE(bs_) do {                                                         \
    _Pragma("unroll")                                                             \
    for (int kk = 0; kk < 2; ++kk) {                                              \
      bf16x8 af_[4], bf_[4];                                                      \
      _Pragma("unroll")                                                           \
      for (int i = 0; i < 4; ++i)                                                 \
        af_[i] = *(const bf16x8*)((const char*)As + (bs_) * 16384 + ra[i] +       \
                                  (((kk * 4 + g4) ^ q7) << 4));                   \
      _Pragma("unroll")                                                           \
      for (int j = 0; j < 4; ++j)                                                 \
        bf_[j] = *(const bf16x8*)((const char*)Bs + (bs_) * 8192 + rbv[j] +       \
                                  (((kk * 4 + g4) ^ q7) << 4));                   \
      _Pragma("unroll")                                                           \
      for (int i = 0; i < 4; ++i)                                                 \
        _Pragma("unroll")                                                         \
        for (int j = 0; j < 4; ++j)                                               \
          acc[i][j] = mfma16(af_[i], bf_[j], acc[i][j]);                          \
    }                                                                             \
  } while (0)

  STAGE(0, 0);
  for (int st = 0; st < nsteps; ++st) {
    __syncthreads();                       // stage(st) drained (compiler vmcnt(0) before barrier)
    if (st + 1 < nsteps) STAGE(st + 1, (st + 1) & 1);   // fly under compute
    COMPUTE(st & 1);
  }
#undef STAGE
#undef COMPUTE

  // epilogue: per-wave rows wid*64 + i*16 + g4*4 + r, cols n0 + j*16 + r16
  #pragma unroll
  for (int i = 0; i < 4; ++i) {
    int row = m0 + wid * 64 + i * 16 + g4 * 4;
    #pragma unroll
    for (int j = 0; j < 4; ++j) {
      int n = n0 + j * 16 + r16;
      f32x4 v = acc[i][j];
      if constexpr (EPI == 0) {
        int sec = row >> 8;
        int ch = row & 255;
        if (sec < 2) {
          u16x4 pk;
          #pragma unroll
          for (int r = 0; r < 4; ++r) pk[r] = f2b(v[r] + bias[row + r]);
          *(u16x4*)((sec ? o1 : o0) + (size_t)n * 256 + ch) = pk;
        } else {
          #pragma unroll
          for (int r = 0; r < 4; ++r)
            o2[(size_t)(ch + r) * NTOT + n] = f2b(v[r] + bias[row + r]);
        }
      } else if constexpr (EPI == 1) {
        u16x4 pk;
        #pragma unroll
        for (int r = 0; r < 4; ++r) pk[r] = f2b(v[r]);
        *(u16x4*)(o0 + (size_t)n * 256 + row) = pk;
      } else {
        #pragma unroll
        for (int r = 0; r < 4; ++r) v[r] += bias[row + r];
        *(f32x4*)(outF + (size_t)n * 256 + row) = v;
        u16x4 pk;
        #pragma unroll
        for (int r = 0; r < 4; ++r) pk[r] = f2b(v[r]);
        *(u16x4*)(o0 + (size_t)n * 256 + row) = pk;
      }
    }
  }
}

// ---------------- fused masked flash attention over COMPACTED keys ----------------
// theta: [B,N,C] bf16; phic: [B,4096pad,C] bf16 (kept keys); gc: [C,NTOT] bf16 (kept keys per batch)
// kcount[b] = #kept keys. Writes unnormalized partials per split s + (m,l).
__launch_bounds__(512, 2)
__global__ void attn_k(const unsigned short* __restrict__ theta,
                       const unsigned short* __restrict__ phic,
                       const unsigned short* __restrict__ gc,
                       const int* __restrict__ kcount,
                       float* __restrict__ Op0,
                       float* __restrict__ Op1,
                       float2* __restrict__ ml2) {
  int f = blockIdx.x;                 // 256 blocks; XCD = f%8 -> one (b,s) per XCD
  int b = (f & 7) >> 1;
  int s = f & 1;
  int q0 = (f >> 3) * 128;
  int tid = threadIdx.x, lane = tid & 63, wid = tid >> 6;
  int r16 = lane & 15, g4 = lane >> 4;
  const unsigned short* th = theta + (size_t)b * PB;
  const unsigned short* phb = phic + (size_t)b * PB;

  int Kb = kcount[b];
  int nt = (Kb + 63) >> 6;
  int h = (nt + 1) >> 1;
  int t0 = s * h, t1 = min(nt, t0 + h);

  __shared__ __align__(16) unsigned short Kt[2][16384];   // 2 x 32KB
  __shared__ __align__(16) unsigned short Vt[2][16384];   // 2 x 32KB
  __shared__ __align__(16) unsigned short Plds[8][16][72];

  // Q fragments (16 q-rows per wave)
  int qrow = q0 + wid * 16 + r16;
  bf16x8 aq[8];
  #pragma unroll
  for (int ks = 0; ks < 8; ++ks)
    aq[ks] = *(const bf16x8*)(th + (size_t)qrow * CC + ks * 32 + 8 * g4);

  f32x4 O[16];
  #pragma unroll
  for (int cf = 0; cf < 16; ++cf) { O[cf][0] = 0.f; O[cf][1] = 0.f; O[cf][2] = 0.f; O[cf][3] = 0.f; }
  float mrow[4] = {-1e30f, -1e30f, -1e30f, -1e30f};
  float lrow[4] = {0.f, 0.f, 0.f, 0.f};

  bf16x8 kst[4], vst[4];
  if (t0 < t1) {
    int k0g = t0 * 64;
    #pragma unroll
    for (int i = 0; i < 4; ++i) {
      int slot = wid * 4 + i;
      kst[i] = *(const bf16x8*)(phb + (size_t)(k0g + lane) * CC + slot * 8);
      vst[i] = *(const bf16x8*)(gc + (size_t)(i * 64 + lane) * NTOT + b * 4096 + k0g + wid * 8);
    }
    #pragma unroll
    for (int i = 0; i < 4; ++i) {
      int slot = wid * 4 + i;
      *(bf16x8*)&Kt[0][slot * 512 + lane * 8] = kst[i];
      *(bf16x8*)&Vt[0][wid * 2048 + i * 512 + lane * 8] = vst[i];
    }
  }
  __syncthreads();

  #pragma unroll 1
  for (int t = t0; t < t1; ++t) {
    int p = (t - t0) & 1;
    if (t + 1 < t1) {
      int k0g = (t + 1) * 64;
      #pragma unroll
      for (int i = 0; i < 4; ++i) {
        int slot = wid * 4 + i;
        kst[i] = *(const bf16x8*)(phb + (size_t)(k0g + lane) * CC + slot * 8);
        vst[i] = *(const bf16x8*)(gc + (size_t)(i * 64 + lane) * NTOT + b * 4096 + k0g + wid * 8);
      }
    }
    // ---- QK^T ----
    f32x4 S[4];
    #pragma unroll
    for (int ff = 0; ff < 4; ++ff) { S[ff][0] = 0.f; S[ff][1] = 0.f; S[ff][2] = 0.f; S[ff][3] = 0.f; }
    #pragma unroll
    for (int ks = 0; ks < 8; ++ks) {
      #pragma unroll
      for (int ff = 0; ff < 4; ++ff) {
        bf16x8 bk = *(const bf16x8*)&Kt[p][(ks * 4 + g4) * 512 + (ff * 16 + r16) * 8];
        S[ff] = mfma16(aq[ks], bk, S[ff]);
      }
    }
    // ---- online softmax (validity: key index < Kb) ----
    bool mk[4];
    #pragma unroll
    for (int ff = 0; ff < 4; ++ff) mk[ff] = (t * 64 + ff * 16 + r16) < Kb;
    float scr[4];
    #pragma unroll
    for (int r = 0; r < 4; ++r) {
      float v = -1e30f;
      #pragma unroll
      for (int ff = 0; ff < 4; ++ff) v = fmaxf(v, mk[ff] ? S[ff][r] : -1e30f);
      v = fmaxf(v, __shfl_xor(v, 1));
      v = fmaxf(v, __shfl_xor(v, 2));
      v = fmaxf(v, __shfl_xor(v, 4));
      v = fmaxf(v, __shfl_xor(v, 8));
      float nm = fmaxf(mrow[r], v);
      scr[r] = __expf(mrow[r] - nm);
      mrow[r] = nm;
      lrow[r] *= scr[r];
    }
    float ps[4][4];
    float rsum[4] = {0.f, 0.f, 0.f, 0.f};
    #pragma unroll
    for (int ff = 0; ff < 4; ++ff)
      #pragma unroll
      for (int r = 0; r < 4; ++r) {
        float pp = mk[ff] ? __expf(S[ff][r] - mrow[r]) : 0.f;
        ps[ff][r] = pp;
        rsum[r] += pp;
      }
    #pragma unroll
    for (int r = 0; r < 4; ++r) {
      float sm = rsum[r];
      sm += __shfl_xor(sm, 1);
      sm += __shfl_xor(sm, 2);
      sm += __shfl_xor(sm, 4);
      sm += __shfl_xor(sm, 8);
      lrow[r] += sm;
    }
    #pragma unroll
    for (int cf = 0; cf < 16; ++cf) {
      O[cf][0] *= scr[0]; O[cf][1] *= scr[1]; O[cf][2] *= scr[2]; O[cf][3] *= scr[3];
    }
    // ---- P relayout via per-wave LDS bounce ----
    #pragma unroll
    for (int ff = 0; ff < 4; ++ff)
      #pragma unroll
      for (int r = 0; r < 4; ++r)
        Plds[wid][g4 * 4 + r][ff * 16 + r16] = f2b(ps[ff][r]);
    // ---- PV ----
    #pragma unroll
    for (int ks2 = 0; ks2 < 2; ++ks2) {
      bf16x8 ap = *(const bf16x8*)&Plds[wid][r16][ks2 * 32 + 8 * g4];
      #pragma unroll
      for (int cf = 0; cf < 16; ++cf) {
        bf16x8 bv = *(const bf16x8*)&Vt[p][(ks2 * 4 + g4) * 2048 + (cf * 16 + r16) * 8];
        O[cf] = mfma16(ap, bv, O[cf]);
      }
    }
    if (t + 1 < t1) {
      #pragma unroll
      for (int i = 0; i < 4; ++i) {
        int slot = wid * 4 + i;
        *(bf16x8*)&Kt[p ^ 1][slot * 512 + lane * 8] = kst[i];
        *(bf16x8*)&Vt[p ^ 1][wid * 2048 + i * 512 + lane * 8] = vst[i];
      }
    }
    __syncthreads();
  }

  // ---- epilogue: unnormalized partial O (f32) + (m, l) per q-row ----
  float* Opb = (s ? Op1 : Op0) + (size_t)b * NPIX * CC;
  #pragma unroll
  for (int cf = 0; cf < 16; ++cf)
    #pragma unroll
    for (int r = 0; r < 4; ++r)
      Opb[(size_t)(q0 + wid * 16 + g4 * 4 + r) * CC + cf * 16 + r16] = O[cf][r];
  if (r16 == 0) {
    #pragma unroll
    for (int r = 0; r < 4; ++r)
      ml2[(size_t)(s * BB + b) * NPIX + q0 + wid * 16 + g4 * 4 + r] =
          make_float2(mrow[r], lrow[r]);
  }
}

// ---------------- combine the 2 K-split partials -> y bf16 [B,N,C] ----------------
__global__ void attn_combine_k(const float* __restrict__ Op0, const float* __restrict__ Op1,
                               const float2* __restrict__ ml2, unsigned short* __restrict__ y) {
  size_t e = ((size_t)blockIdx.x * 256 + threadIdx.x) * 8;
  int bn = (int)(e >> 8);
  float2 a = ml2[bn];
  float2 c = ml2[16384 + bn];
  float M = fmaxf(a.x, c.x);
  float e0 = __expf(a.x - M), e1 = __expf(c.x - M);
  float L = a.y * e0 + c.y * e1;
  float sc = L > 1e-30f ? 1.f / L : 0.f;
  e0 *= sc; e1 *= sc;
  f32x4 p0 = *(const f32x4*)&Op0[e];
  f32x4 p1 = *(const f32x4*)&Op0[e + 4];
  f32x4 q0 = *(const f32x4*)&Op1[e];
  f32x4 q1 = *(const f32x4*)&Op1[e + 4];
  bf16x8 r;
  #pragma unroll
  for (int j = 0; j < 4; ++j) {
    r[j]     = (short)f2b(p0[j] * e0 + q0[j] * e1);
    r[4 + j] = (short)f2b(p1[j] * e0 + q1[j] * e1);
  }
  *(bf16x8*)&y[e] = r;
}

// ---------------- instance-norm stats (vectorized bf16x8 reads) ----------------
__global__ void in_stats_k(const unsigned short* __restrict__ v,
                           float* __restrict__ psum, float* __restrict__ psumsq) {
  int p = blockIdx.x;          // 32 chunks of 128 pixel-rows
  int b = blockIdx.y;
  int tid = threadIdx.x;       // 256
  int cg = (tid & 31) * 8;     // channel slab
  int rsub = tid >> 5;         // 0..7
  const unsigned short* base = v + (size_t)b * PB + (size_t)p * 128 * CC;
  float s[8] = {}, s2[8] = {};
  for (int it = 0; it < 16; ++it) {
    int row = rsub + it * 8;
    bf16x8 x = *(const bf16x8*)(base + (size_t)row * CC + cg);
    #pragma unroll
    for (int j = 0; j < 8; ++j) {
      float f = b2f((unsigned short)x[j]);
      s[j] += f; s2[j] += f * f;
    }
  }
  __shared__ float redS[8][256];
  __shared__ float redQ[8][256];
  #pragma unroll
  for (int j = 0; j < 8; ++j) { redS[rsub][cg + j] = s[j]; redQ[rsub][cg + j] = s2[j]; }
  __syncthreads();
  float a = 0.f, q = 0.f;
  #pragma unroll
  for (int r = 0; r < 8; ++r) { a += redS[r][tid]; q += redQ[r][tid]; }
  int o = (p * BB + b) * CC + tid;
  psum[o] = a; psumsq[o] = q;
}

__global__ void in_finalize_k(const float* __restrict__ psum, const float* __restrict__ psumsq,
                              float* __restrict__ mu, float* __restrict__ rs) {
  int bc = blockIdx.x * 256 + threadIdx.x;
  int b = bc >> 8, c = bc & 255;
  float s = 0.f, s2 = 0.f;
  for (int p = 0; p < 32; ++p) {
    s  += psum[(p * BB + b) * CC + c];
    s2 += psumsq[(p * BB + b) * CC + c];
  }
  float m_ = s * (1.f / 4096.f);
  float var = s2 * (1.f / 4096.f) - m_ * m_;
  var = var > 0.f ? var : 0.f;
  mu[bc] = m_;
  rs[bc] = rsqrtf(var + 1e-5f);
}

// ---------------- IN+ReLU apply ----------------
__global__ void normrelu_k(const unsigned short* __restrict__ src,
                           const float* __restrict__ mu, const float* __restrict__ rs,
                           unsigned short* __restrict__ dst) {
  size_t idx = (size_t)blockIdx.x * 256 + threadIdx.x;
  size_t e = idx * 8;
  if (e >= (size_t)BB * PB) return;
  int c = (int)(e & 255);
  int b = (int)(e >> 20);
  const float* mup = mu + b * 256 + c;
  const float* rsp = rs + b * 256 + c;
  bf16x8 v = *(const bf16x8*)(src + e);
  bf16x8 ov;
  #pragma unroll
  for (int j = 0; j < 8; ++j) {
    float f = (b2f((unsigned short)v[j]) - mup[j]) * rsp[j];
    ov[j] = (short)f2b(f > 0.f ? f : 0.f);
  }
  *(bf16x8*)(dst + e) = ov;
}

// ---------------- residual += IN(conv2), keep f32 + bf16 ----------------
__global__ void resupdate_k(const unsigned short* __restrict__ c2,
                            const float* __restrict__ mu, const float* __restrict__ rs,
                            float* __restrict__ r, unsigned short* __restrict__ rb) {
  size_t idx = (size_t)blockIdx.x * 256 + threadIdx.x;
  size_t e = idx * 8;
  if (e >= (size_t)BB * PB) return;
  int c = (int)(e & 255);
  int b = (int)(e >> 20);
  const float* mup = mu + b * 256 + c;
  const float* rsp = rs + b * 256 + c;
  bf16x8 v = *(const bf16x8*)(c2 + e);
  bf16x8 ov;
  #pragma unroll
  for (int j = 0; j < 8; ++j) {
    float f = r[e + j] + (b2f((unsigned short)v[j]) - mup[j]) * rsp[j];
    r[e + j] = f;
    ov[j] = (short)f2b(f);
  }
  *(bf16x8*)(rb + e) = ov;
}

// ---------------- final blend ----------------
__global__ void final_blend_k(const float* __restrict__ x, const float* __restrict__ r,
                              const float* __restrict__ m, float* __restrict__ out) {
  __shared__ float T[64][65];
  int b = blockIdx.z;
  int n0 = blockIdx.x * 64, c0 = blockIdx.y * 64;
  int tx = threadIdx.x, ty = threadIdx.y;
  #pragma unroll
  for (int i = 0; i < 16; ++i) {
    int nl = ty + i * 4;
    T[nl][tx] = r[(size_t)b * PB + (size_t)(n0 + nl) * CC + c0 + tx];
  }
  __syncthreads();
  #pragma unroll
  for (int i = 0; i < 16; ++i) {
    int cl = ty + i * 4;
    int cg = c0 + cl, ng = n0 + tx;
    float mv = m[b * NPIX + ng];
    float xv = x[(size_t)b * PB + (size_t)cg * NPIX + ng];
    out[(size_t)b * PB + (size_t)cg * NPIX + ng] = mv * xv + (1.f - mv) * T[tx][cl];
  }
}

// ---------------- workspace layout (bytes) ----------------
#define OFF_M    0UL            // mask f32 [B,N] 64KB
#define OFF_XT   65536UL        // 8MB: xT -> phic (gather) -> ybuf (combine)
#define OFF_TH   8454144UL      // 8MB: theta [B,N,C] -> cbuf
#define OFF_PH   16842752UL     // 8MB: phi [B,N,C] -> gc -> hbuf
#define OFF_G    25231360UL     // 8MB: g [C,NTOT] -> rb
#define OFF_R    33619968UL     // 16MB: op0 -> rbuf f32 [B,N,C]
#define OFF_W1   50397184UL     // 1x1 weights bf16 stacked: theta|phi|g|W
#define OFF_WK   50921472UL     // res conv weights bf16 [6][9][256][256]
#define OFF_MU   57999360UL
#define OFF_RS   58003456UL
#define OFF_PS   58007552UL
#define OFF_PS2  58138624UL
#define OFF_OP1  58269696UL     // attn partial split 1 f32 (16MB)
#define OFF_ML   75046912UL     // (m,l) float2 [2][B][N] (256KB)
#define OFF_CI   75309056UL     // compact indices int [B][4096] (64KB)
#define OFF_KC   75374592UL     // kcount int[4]
#define OFF_BIAS 75374848UL     // stacked bias f32 [1024]

extern "C" void kernel_launch(void* const* d_in, const int* in_sizes, int n_in,
                              void* d_out, int out_size, void* d_ws, size_t ws_size,
                              hipStream_t stream) {
  const float* x       = (const float*)d_in[0];
  const float* maskp   = (const float*)d_in[1];
  const float* g_w     = (const float*)d_in[2];
  const float* g_b     = (const float*)d_in[3];
  const float* theta_w = (const float*)d_in[4];
  const float* theta_b = (const float*)d_in[5];
  const float* phi_w   = (const float*)d_in[6];
  const float* phi_b   = (const float*)d_in[7];
  const float* W_w     = (const float*)d_in[8];
  const float* W_b     = (const float*)d_in[9];
  const float* res_w1  = (const float*)d_in[10];
  const float* res_w2  = (const float*)d_in[12];
  float* out = (float*)d_out;
  char* ws = (char*)d_ws;

  float*          mbuf = (float*)(ws + OFF_M);
  unsigned short* xT   = (unsigned short*)(ws + OFF_XT);
  unsigned short* phic = (unsigned short*)(ws + OFF_XT);   // alias: xT dead after TPG gemm
  unsigned short* ybuf = (unsigned short*)(ws + OFF_XT);   // alias: phic dead after attn
  unsigned short* thb  = (unsigned short*)(ws + OFF_TH);
  unsigned short* cbuf = (unsigned short*)(ws + OFF_TH);
  unsigned short* phb  = (unsigned short*)(ws + OFF_PH);
  unsigned short* gc   = (unsigned short*)(ws + OFF_PH);   // alias: phb dead after gather_phi
  unsigned short* hbuf = (unsigned short*)(ws + OFF_PH);   // alias: gc dead after attn
  unsigned short* gbuf = (unsigned short*)(ws + OFF_G);
  unsigned short* rb   = (unsigned short*)(ws + OFF_G);    // alias: gbuf dead after gather_g
  float*          rbuf = (float*)(ws + OFF_R);
  float*          op0  = (float*)(ws + OFF_R);             // alias: dead before W_y gemm
  float*          op1  = (float*)(ws + OFF_OP1);
  float2*         ml2  = (float2*)(ws + OFF_ML);
  int*            ci   = (int*)(ws + OFF_CI);
  int*            kc   = (int*)(ws + OFF_KC);
  float*          biasS= (float*)(ws + OFF_BIAS);
  unsigned short* thw  = (unsigned short*)(ws + OFF_W1);   // stacked theta|phi|g|W
  unsigned short* Www  = (unsigned short*)(ws + OFF_W1 + 393216);
  unsigned short* wkres= (unsigned short*)(ws + OFF_WK);
  float*          mu   = (float*)(ws + OFF_MU);
  float*          rs   = (float*)(ws + OFF_RS);
  float*          psum = (float*)(ws + OFF_PS);
  float*          psq  = (float*)(ws + OFF_PS2);

  // prep
  repack_w1x1_k<<<256, 256, 0, stream>>>(theta_w, phi_w, g_w, W_w, thw);
  repack_res_k<<<6912, 256, 0, stream>>>(res_w1, res_w2, wkres);
  repack_bias_k<<<4, 256, 0, stream>>>(theta_b, phi_b, g_b, W_b, biasS);
  prep_mask_k<<<64, 256, 0, stream>>>(maskp, mbuf);
  transpose_x_k<<<dim3(64, 4, 4), dim3(64, 4), 0, stream>>>(x, xT);

  // fused theta|phi|g projection (M=768)
  gemm_w<0, 1><<<dim3(256, 6), 128, 0, stream>>>(thw, xT, biasS, nullptr, thb, phb, gbuf);

  // key compaction
  mask_scan_k<<<4, 256, 0, stream>>>(mbuf, ci, kc);
  gather_phi_k<<<dim3(512, 4), 256, 0, stream>>>(phb, ci, kc, phic);
  gather_g_k<<<dim3(16, 256, 4), 256, 0, stream>>>(gbuf, ci, kc, gc);

  // flash attention over compacted keys (K-split 2) + combine
  attn_k<<<256, 512, 0, stream>>>(thb, phic, gc, kc, op0, op1, ml2);
  attn_combine_k<<<2048, 256, 0, stream>>>(op0, op1, ml2, ybuf);

  // W_y projection -> residual f32 + bf16
  gemm_w<2, 1><<<dim3(256, 2), 128, 0, stream>>>(Www, ybuf, biasS + 768, rbuf, rb, nullptr, nullptr);

  // 3 residual blocks
  for (int i = 0; i < 3; ++i) {
    gemm_w<1, 9><<<dim3(256, 2), 128, 0, stream>>>(
        wkres + (size_t)(2 * i) * 589824, rb, nullptr, nullptr, cbuf, nullptr, nullptr);
    in_stats_k<<<dim3(32, 4), 256, 0, stream>>>(cbuf, psum, psq);
    in_finalize_k<<<4, 256, 0, stream>>>(psum, psq, mu, rs);
    normrelu_k<<<2048, 256, 0, stream>>>(cbuf, mu, rs, hbuf);
    gemm_w<1, 9><<<dim3(256, 2), 128, 0, stream>>>(
        wkres + (size_t)(2 * i + 1) * 589824, hbuf, nullptr, nullptr, cbuf, nullptr, nullptr);
    in_stats_k<<<dim3(32, 4), 256, 0, stream>>>(cbuf, psum, psq);
    in_finalize_k<<<4, 256, 0, stream>>>(psum, psq, mu, rs);
    resupdate_k<<<2048, 256, 0, stream>>>(cbuf, mu, rs, rbuf, rb);
  }

  // final blend + transpose to [B,C,H,W]
  final_blend_k<<<dim3(64, 4, 4), dim3(64, 4), 0, stream>>>(x, rbuf, mbuf, out);
}

// Round 7
// 499.823 us; speedup vs baseline: 1.1796x; 1.1796x over previous
//
#include <hip/hip_runtime.h>

// Problem constants
#define BB   4
#define CC   256
#define NPIX 4096            // 64*64
#define PB   1048576         // per-batch elements: NPIX*CC
#define NTOT 16384           // B * NPIX (batch folded into GEMM N)

typedef __attribute__((ext_vector_type(8))) short bf16x8;
typedef __attribute__((ext_vector_type(4))) float f32x4;
typedef __attribute__((ext_vector_type(4))) unsigned short u16x4;

__device__ __forceinline__ unsigned short f2b(float f) {
  union { float f; unsigned u; } v; v.f = f;
  unsigned r = v.u + 0x7fffu + ((v.u >> 16) & 1u);
  return (unsigned short)(r >> 16);
}
__device__ __forceinline__ float b2f(unsigned short h) {
  union { unsigned u; float f; } v; v.u = ((unsigned)h) << 16;
  return v.f;
}
__device__ __forceinline__ f32x4 mfma16(bf16x8 a, bf16x8 b, f32x4 c) {
  return __builtin_amdgcn_mfma_f32_16x16x32_bf16(a, b, c, 0, 0, 0);
}
// async global->LDS, 16B per lane. LDS dst = wave-uniform base + lane*16 (linear).
__device__ __forceinline__ void gload_lds16(const unsigned short* g, unsigned short* l) {
  __builtin_amdgcn_global_load_lds(
      (const __attribute__((address_space(1))) unsigned int*)g,
      (__attribute__((address_space(3))) unsigned int*)l, 16, 0, 0);
}
// reflect-pad(1) pixel remap for 64x64 image
__device__ __forceinline__ int remap_px(int n, int dh, int dw) {
  int h = (n >> 6) + dh;
  int w = (n & 63) + dw;
  h = h < 0 ? 1 : (h > 63 ? 62 : h);
  w = w < 0 ? 1 : (w > 63 ? 62 : w);
  return (h << 6) | w;
}

// ---------------- weight / bias repack ----------------
__global__ void repack_w1x1_k(const float* __restrict__ tw, const float* __restrict__ pw,
                              const float* __restrict__ gw, const float* __restrict__ Ww,
                              unsigned short* __restrict__ dst) {
  int i = blockIdx.x * 256 + threadIdx.x;          // 65536 total
  dst[i]           = f2b(tw[i]);
  dst[65536 + i]   = f2b(pw[i]);
  dst[131072 + i]  = f2b(gw[i]);
  dst[196608 + i]  = f2b(Ww[i]);
}

__global__ void repack_bias_k(const float* __restrict__ tb, const float* __restrict__ pb,
                              const float* __restrict__ gb, const float* __restrict__ Wb,
                              float* __restrict__ bias) {
  int i = blockIdx.x * 256 + threadIdx.x;          // 1024
  float v;
  if (i < 256) v = tb[i];
  else if (i < 512) v = pb[i - 256];
  else if (i < 768) v = gb[i - 512];
  else v = Wb[i - 768];
  bias[i] = v;
}

__global__ void repack_res_k(const float* __restrict__ w1, const float* __restrict__ w2,
                             unsigned short* __restrict__ wk) {
  int idx = blockIdx.x * 256 + threadIdx.x;        // 3*256*256*9 = 1769472 total
  if (idx >= 1769472) return;
  int t = idx % 9;
  int rest = idx / 9;                              // (i*256+o)*256+c
  int c = rest & 255;
  int o = (rest >> 8) & 255;
  int i = rest >> 16;
  size_t d = (size_t)t * 65536 + o * 256 + c;      // [t][o][c] within one conv
  wk[(size_t)(2 * i)     * 589824 + d] = f2b(w1[idx]);
  wk[(size_t)(2 * i + 1) * 589824 + d] = f2b(w2[idx]);
}

// ---------------- mask prep ----------------
__global__ void prep_mask_k(const float* __restrict__ mask, float* __restrict__ m) {
  int idx = blockIdx.x * 256 + threadIdx.x;        // B*4096
  if (idx >= BB * NPIX) return;
  int b = idx >> 12, n = idx & 4095;
  int h = n >> 6, w = n & 63;
  const float* M = mask + b * 1024;
  float sh = 0.5f * h - 0.25f, sw = 0.5f * w - 0.25f;
  int h0 = (int)floorf(sh), w0 = (int)floorf(sw);
  float th = sh - h0, tw = sw - w0;
  int h0c = min(max(h0, 0), 31), h1c = min(max(h0 + 1, 0), 31);
  int w0c = min(max(w0, 0), 31), w1c = min(max(w0 + 1, 0), 31);
  float v = (1.f - th) * ((1.f - tw) * M[h0c * 32 + w0c] + tw * M[h0c * 32 + w1c])
          +        th  * ((1.f - tw) * M[h1c * 32 + w0c] + tw * M[h1c * 32 + w1c]);
  float inv = v > 0.f ? 0.f : 1.f;
  float tmp = 1.f - M[(h >> 1) * 32 + (w >> 1)];
  m[idx] = inv * tmp;                              // binary {0,1}
}

// ---------------- key compaction: scan + gathers ----------------
__global__ void mask_scan_k(const float* __restrict__ mbuf, int* __restrict__ ci,
                            int* __restrict__ kcount) {
  int b = blockIdx.x;
  int tid = threadIdx.x;                           // 256, 16 pix each
  __shared__ int sc[256];
  const float* mb = mbuf + b * 4096;
  int n0 = tid * 16, cnt = 0;
  float mv[16];
  #pragma unroll
  for (int i = 0; i < 16; ++i) { mv[i] = mb[n0 + i]; cnt += mv[i] > 0.f ? 1 : 0; }
  sc[tid] = cnt;
  __syncthreads();
  for (int off = 1; off < 256; off <<= 1) {
    int v = sc[tid];
    int u = tid >= off ? sc[tid - off] : 0;
    __syncthreads();
    sc[tid] = v + u;
    __syncthreads();
  }
  int base = sc[tid] - cnt;                        // exclusive prefix
  int* cib = ci + b * 4096;
  #pragma unroll
  for (int i = 0; i < 16; ++i)
    if (mv[i] > 0.f) cib[base++] = n0 + i;
  if (tid == 255) kcount[b] = sc[255];
}

__global__ void gather_phi_k(const unsigned short* __restrict__ phb, const int* __restrict__ ci,
                             const int* __restrict__ kcount, unsigned short* __restrict__ phic) {
  int b = blockIdx.y;
  int Kb = kcount[b];
  int pad = (Kb + 63) & ~63;
  int j = blockIdx.x * 8 + (threadIdx.x >> 5);
  int cl = threadIdx.x & 31;
  if (j >= pad) return;
  bf16x8 v;
  if (j < Kb) {
    v = *(const bf16x8*)(phb + (size_t)b * PB + (size_t)ci[b * 4096 + j] * 256 + cl * 8);
  } else {
    for (int t = 0; t < 8; ++t) v[t] = 0;
  }
  *(bf16x8*)(phic + (size_t)b * PB + (size_t)j * 256 + cl * 8) = v;
}

__global__ void gather_g_k(const unsigned short* __restrict__ gbuf, const int* __restrict__ ci,
                           const int* __restrict__ kcount, unsigned short* __restrict__ gc) {
  int b = blockIdx.z;
  int Kb = kcount[b];
  int pad = (Kb + 63) & ~63;
  int c = blockIdx.y;
  int j = blockIdx.x * 256 + threadIdx.x;
  if (j >= pad) return;
  unsigned short v = 0;
  if (j < Kb) v = gbuf[(size_t)c * NTOT + b * 4096 + ci[b * 4096 + j]];
  gc[(size_t)c * NTOT + b * 4096 + j] = v;
}

// ---------------- x transpose: [B,C,N] f32 -> [B,N,C] bf16 ----------------
__global__ void transpose_x_k(const float* __restrict__ x, unsigned short* __restrict__ xT) {
  __shared__ float T[64][65];
  int b = blockIdx.z;
  int n0 = blockIdx.x * 64, c0 = blockIdx.y * 64;
  int tx = threadIdx.x, ty = threadIdx.y;
  const float* xb = x + (size_t)b * PB;
  #pragma unroll
  for (int i = 0; i < 16; ++i) {
    int cl = ty + i * 4;
    T[cl][tx] = xb[(size_t)(c0 + cl) * NPIX + n0 + tx];
  }
  __syncthreads();
  unsigned short* ob = xT + (size_t)b * PB;
  #pragma unroll
  for (int i = 0; i < 16; ++i) {
    int nl = ty + i * 4;
    ob[(size_t)(n0 + nl) * CC + c0 + tx] = f2b(T[tx][nl]);
  }
}

// ---------------- weight-stationary GEMM: C[M,NTOT] = A[M,K] * Bact[NTOT,K]^T ----------------
// v3: TM=128, TN=128, BK=64, 256 threads (4 waves 2x2), per-wave 64x64 tile
// (0.5 ds_read/MFMA). global_load_lds, XOR swizzle, double-buffer + stage-ahead,
// XCD-chunked n-tiles. KSPLIT: blockIdx.z takes steps [z*nsteps/KS, ...) -> more blocks/CU.
// EPI 0: fused theta|phi|g (M=768, +bias); EPI 1: bf16 [B,N,C]; EPI 2: f32+bf16 (+bias);
// EPI 3: f32 partial (no bias) -> split0: outF, split1: (float*)o0.
template <int EPI, int TAPS, int KSPLIT>
__launch_bounds__(256, 2)
__global__ void gemm_w(const unsigned short* __restrict__ A,
                       const unsigned short* __restrict__ Bact,
                       const float* __restrict__ bias,
                       float* __restrict__ outF,
                       unsigned short* __restrict__ o0,
                       unsigned short* __restrict__ o1,
                       unsigned short* __restrict__ o2) {
  int m0 = blockIdx.y * 128;
  int bxs = (blockIdx.x & 7) * 16 + (blockIdx.x >> 3);   // XCD-chunked (128 n-tiles = 8x16)
  int n0 = bxs * 128;
  int tid = threadIdx.x, lane = tid & 63, wid = tid >> 6;  // 4 waves, 2x2
  int wm = wid >> 1, wn = wid & 1;
  int r16 = lane & 15, g4 = lane >> 4;
  __shared__ __align__(16) unsigned short As[2 * 8192];   // 2 x 128 rows x 128B
  __shared__ __align__(16) unsigned short Bs[2 * 8192];   // 2 x 128 rows x 128B
  f32x4 acc[4][4] = {};
  // staging geometry: issue q covers LDS bytes L = tid*16 + q*4096 (q=0..3); 256 thr
  int r0 = tid >> 3;                                     // base row (L>>7 for q=0)
  int scol = ((((tid * 16) & 127) ^ ((r0 & 7) << 4)) >> 1);  // pre-swizzled col (elems)
  // LDS read bases (bytes); rows 16-aligned per fragment so row&7 == r16&7
  int q7 = r16 & 7;
  int ra[4], rbv[4];
  #pragma unroll
  for (int i = 0; i < 4; ++i) ra[i] = (wm * 64 + i * 16 + r16) * 128;
  #pragma unroll
  for (int j = 0; j < 4; ++j) rbv[j] = (wn * 64 + j * 16 + r16) * 128;

  const int nsteps = TAPS * 4;
  const int span = nsteps / KSPLIT;
  const int s0 = (KSPLIT > 1 ? blockIdx.z : 0) * span;
  const int s1 = s0 + span;

#define STAGE(st_, bs_) do {                                                      \
    int tap_ = (st_) >> 2, k0_ = ((st_) & 3) * 64;                                \
    const unsigned short* At_ = A + tap_ * 65536;                                 \
    _Pragma("unroll")                                                             \
    for (int q = 0; q < 4; ++q)                                                   \
      gload_lds16(At_ + (size_t)(m0 + r0 + q * 32) * 256 + k0_ + scol,            \
                  &As[(bs_) * 8192 + tid * 8 + q * 2048]);                        \
    _Pragma("unroll")                                                             \
    for (int q = 0; q < 4; ++q) {                                                 \
      int n_ = n0 + r0 + q * 32;                                                  \
      int bsrc_ = n_;                                                             \
      if (TAPS == 9) bsrc_ = (n_ & ~4095) | remap_px(n_ & 4095, tap_ / 3 - 1, tap_ % 3 - 1); \
      gload_lds16(Bact + (size_t)bsrc_ * 256 + k0_ + scol,                        \
                  &Bs[(bs_) * 8192 + tid * 8 + q * 2048]);                        \
    }                                                                             \
  } while (0)

#define COMPUTE(bs_) do {                                                         \
    _Pragma("unroll")                                                             \
    for (int kk = 0; kk < 2; ++kk) {                                              \
      bf16x8 af_[4], bf_[4];                                                      \
      _Pragma("unroll")                                                           \
      for (int i = 0; i < 4; ++i)                                                 \
        af_[i] = *(const bf16x8*)((const char*)As + (bs_) * 16384 + ra[i] +       \
                                  (((kk * 4 + g4) ^ q7) << 4));                   \
      _Pragma("unroll")                                                           \
      for (int j = 0; j < 4; ++j)                                                 \
        bf_[j] = *(const bf16x8*)((const char*)Bs + (bs_) * 16384 + rbv[j] +      \
                                  (((kk * 4 + g4) ^ q7) << 4));                   \
      _Pragma("unroll")                                                           \
      for (int i = 0; i < 4; ++i)                                                 \
        _Pragma("unroll")                                                         \
        for (int j = 0; j < 4; ++j)                                               \
          acc[i][j] = mfma16(af_[i], bf_[j], acc[i][j]);                          \
    }                                                                             \
  } while (0)

  STAGE(s0, 0);
  for (int st = s0; st < s1; ++st) {
    __syncthreads();                       // stage(st) drained before compute/overwrite
    if (st + 1 < s1) STAGE(st + 1, (st + 1 - s0) & 1);   // fly under compute
    COMPUTE((st - s0) & 1);
  }
#undef STAGE
#undef COMPUTE

  // epilogue: rows m0 + wm*64 + i*16 + g4*4 + r, cols n0 + wn*64 + j*16 + r16
  #pragma unroll
  for (int i = 0; i < 4; ++i) {
    int row = m0 + wm * 64 + i * 16 + g4 * 4;
    #pragma unroll
    for (int j = 0; j < 4; ++j) {
      int n = n0 + wn * 64 + j * 16 + r16;
      f32x4 v = acc[i][j];
      if constexpr (EPI == 0) {
        int sec = row >> 8;
        int ch = row & 255;
        if (sec < 2) {
          u16x4 pk;
          #pragma unroll
          for (int r = 0; r < 4; ++r) pk[r] = f2b(v[r] + bias[row + r]);
          *(u16x4*)((sec ? o1 : o0) + (size_t)n * 256 + ch) = pk;
        } else {
          #pragma unroll
          for (int r = 0; r < 4; ++r)
            o2[(size_t)(ch + r) * NTOT + n] = f2b(v[r] + bias[row + r]);
        }
      } else if constexpr (EPI == 1) {
        u16x4 pk;
        #pragma unroll
        for (int r = 0; r < 4; ++r) pk[r] = f2b(v[r]);
        *(u16x4*)(o0 + (size_t)n * 256 + row) = pk;
      } else if constexpr (EPI == 2) {
        #pragma unroll
        for (int r = 0; r < 4; ++r) v[r] += bias[row + r];
        *(f32x4*)(outF + (size_t)n * 256 + row) = v;
        u16x4 pk;
        #pragma unroll
        for (int r = 0; r < 4; ++r) pk[r] = f2b(v[r]);
        *(u16x4*)(o0 + (size_t)n * 256 + row) = pk;
      } else {
        float* dst = blockIdx.z ? (float*)o0 : outF;
        *(f32x4*)&dst[(size_t)n * 256 + row] = v;
      }
    }
  }
}

// ---------------- combine K-split partials -> bf16 + IN partial stats ----------------
__global__ void combine_stats_k(const float* __restrict__ p0, const float* __restrict__ p1,
                                unsigned short* __restrict__ cb,
                                float* __restrict__ psum, float* __restrict__ psq) {
  int p = blockIdx.x;          // 32 chunks of 128 pixel-rows
  int b = blockIdx.y;
  int tid = threadIdx.x;       // 256
  int cg = (tid & 31) * 8;
  int rsub = tid >> 5;         // 0..7
  size_t base = ((size_t)b * 4096 + p * 128) * 256;
  float s[8] = {}, s2[8] = {};
  for (int it = 0; it < 16; ++it) {
    int row = rsub + it * 8;
    size_t e = base + (size_t)row * 256 + cg;
    f32x4 a0 = *(const f32x4*)&p0[e];
    f32x4 a1 = *(const f32x4*)&p0[e + 4];
    f32x4 c0 = *(const f32x4*)&p1[e];
    f32x4 c1 = *(const f32x4*)&p1[e + 4];
    bf16x8 ov;
    #pragma unroll
    for (int j = 0; j < 4; ++j) {
      float f = a0[j] + c0[j];
      ov[j] = (short)f2b(f); s[j] += f; s2[j] += f * f;
    }
    #pragma unroll
    for (int j = 0; j < 4; ++j) {
      float f = a1[j] + c1[j];
      ov[4 + j] = (short)f2b(f); s[4 + j] += f; s2[4 + j] += f * f;
    }
    *(bf16x8*)&cb[e] = ov;
  }
  __shared__ float redS[8][256];
  __shared__ float redQ[8][256];
  #pragma unroll
  for (int j = 0; j < 8; ++j) { redS[rsub][cg + j] = s[j]; redQ[rsub][cg + j] = s2[j]; }
  __syncthreads();
  float a = 0.f, q = 0.f;
  #pragma unroll
  for (int r = 0; r < 8; ++r) { a += redS[r][tid]; q += redQ[r][tid]; }
  int o = (p * BB + b) * CC + tid;
  psum[o] = a; psq[o] = q;
}

// ---------------- fused masked flash attention over COMPACTED keys ----------------
__launch_bounds__(512, 2)
__global__ void attn_k(const unsigned short* __restrict__ theta,
                       const unsigned short* __restrict__ phic,
                       const unsigned short* __restrict__ gc,
                       const int* __restrict__ kcount,
                       float* __restrict__ Op0,
                       float* __restrict__ Op1,
                       float2* __restrict__ ml2) {
  int f = blockIdx.x;                 // 256 blocks
  int b = (f & 7) >> 1;
  int s = f & 1;
  int q0 = (f >> 3) * 128;
  int tid = threadIdx.x, lane = tid & 63, wid = tid >> 6;
  int r16 = lane & 15, g4 = lane >> 4;
  const unsigned short* th = theta + (size_t)b * PB;
  const unsigned short* phb = phic + (size_t)b * PB;

  int Kb = kcount[b];
  int nt = (Kb + 63) >> 6;
  int h = (nt + 1) >> 1;
  int t0 = s * h, t1 = min(nt, t0 + h);

  __shared__ __align__(16) unsigned short Kt[2][16384];   // 2 x 32KB
  __shared__ __align__(16) unsigned short Vt[2][16384];   // 2 x 32KB
  __shared__ __align__(16) unsigned short Plds[8][16][72];

  int qrow = q0 + wid * 16 + r16;
  bf16x8 aq[8];
  #pragma unroll
  for (int ks = 0; ks < 8; ++ks)
    aq[ks] = *(const bf16x8*)(th + (size_t)qrow * CC + ks * 32 + 8 * g4);

  f32x4 O[16];
  #pragma unroll
  for (int cf = 0; cf < 16; ++cf) { O[cf][0] = 0.f; O[cf][1] = 0.f; O[cf][2] = 0.f; O[cf][3] = 0.f; }
  float mrow[4] = {-1e30f, -1e30f, -1e30f, -1e30f};
  float lrow[4] = {0.f, 0.f, 0.f, 0.f};

  bf16x8 kst[4], vst[4];
  if (t0 < t1) {
    int k0g = t0 * 64;
    #pragma unroll
    for (int i = 0; i < 4; ++i) {
      int slot = wid * 4 + i;
      kst[i] = *(const bf16x8*)(phb + (size_t)(k0g + lane) * CC + slot * 8);
      vst[i] = *(const bf16x8*)(gc + (size_t)(i * 64 + lane) * NTOT + b * 4096 + k0g + wid * 8);
    }
    #pragma unroll
    for (int i = 0; i < 4; ++i) {
      int slot = wid * 4 + i;
      *(bf16x8*)&Kt[0][slot * 512 + lane * 8] = kst[i];
      *(bf16x8*)&Vt[0][wid * 2048 + i * 512 + lane * 8] = vst[i];
    }
  }
  __syncthreads();

  #pragma unroll 1
  for (int t = t0; t < t1; ++t) {
    int p = (t - t0) & 1;
    if (t + 1 < t1) {
      int k0g = (t + 1) * 64;
      #pragma unroll
      for (int i = 0; i < 4; ++i) {
        int slot = wid * 4 + i;
        kst[i] = *(const bf16x8*)(phb + (size_t)(k0g + lane) * CC + slot * 8);
        vst[i] = *(const bf16x8*)(gc + (size_t)(i * 64 + lane) * NTOT + b * 4096 + k0g + wid * 8);
      }
    }
    // ---- QK^T ----
    f32x4 S[4];
    #pragma unroll
    for (int ff = 0; ff < 4; ++ff) { S[ff][0] = 0.f; S[ff][1] = 0.f; S[ff][2] = 0.f; S[ff][3] = 0.f; }
    #pragma unroll
    for (int ks = 0; ks < 8; ++ks) {
      #pragma unroll
      for (int ff = 0; ff < 4; ++ff) {
        bf16x8 bk = *(const bf16x8*)&Kt[p][(ks * 4 + g4) * 512 + (ff * 16 + r16) * 8];
        S[ff] = mfma16(aq[ks], bk, S[ff]);
      }
    }
    // ---- online softmax (validity: key index < Kb) ----
    bool mk[4];
    #pragma unroll
    for (int ff = 0; ff < 4; ++ff) mk[ff] = (t * 64 + ff * 16 + r16) < Kb;
    float scr[4];
    #pragma unroll
    for (int r = 0; r < 4; ++r) {
      float v = -1e30f;
      #pragma unroll
      for (int ff = 0; ff < 4; ++ff) v = fmaxf(v, mk[ff] ? S[ff][r] : -1e30f);
      v = fmaxf(v, __shfl_xor(v, 1));
      v = fmaxf(v, __shfl_xor(v, 2));
      v = fmaxf(v, __shfl_xor(v, 4));
      v = fmaxf(v, __shfl_xor(v, 8));
      float nm = fmaxf(mrow[r], v);
      scr[r] = __expf(mrow[r] - nm);
      mrow[r] = nm;
      lrow[r] *= scr[r];
    }
    float ps[4][4];
    float rsum[4] = {0.f, 0.f, 0.f, 0.f};
    #pragma unroll
    for (int ff = 0; ff < 4; ++ff)
      #pragma unroll
      for (int r = 0; r < 4; ++r) {
        float pp = mk[ff] ? __expf(S[ff][r] - mrow[r]) : 0.f;
        ps[ff][r] = pp;
        rsum[r] += pp;
      }
    #pragma unroll
    for (int r = 0; r < 4; ++r) {
      float sm = rsum[r];
      sm += __shfl_xor(sm, 1);
      sm += __shfl_xor(sm, 2);
      sm += __shfl_xor(sm, 4);
      sm += __shfl_xor(sm, 8);
      lrow[r] += sm;
    }
    #pragma unroll
    for (int cf = 0; cf < 16; ++cf) {
      O[cf][0] *= scr[0]; O[cf][1] *= scr[1]; O[cf][2] *= scr[2]; O[cf][3] *= scr[3];
    }
    // ---- P relayout via per-wave LDS bounce ----
    #pragma unroll
    for (int ff = 0; ff < 4; ++ff)
      #pragma unroll
      for (int r = 0; r < 4; ++r)
        Plds[wid][g4 * 4 + r][ff * 16 + r16] = f2b(ps[ff][r]);
    // ---- PV ----
    #pragma unroll
    for (int ks2 = 0; ks2 < 2; ++ks2) {
      bf16x8 ap = *(const bf16x8*)&Plds[wid][r16][ks2 * 32 + 8 * g4];
      #pragma unroll
      for (int cf = 0; cf < 16; ++cf) {
        bf16x8 bv = *(const bf16x8*)&Vt[p][(ks2 * 4 + g4) * 2048 + (cf * 16 + r16) * 8];
        O[cf] = mfma16(ap, bv, O[cf]);
      }
    }
    if (t + 1 < t1) {
      #pragma unroll
      for (int i = 0; i < 4; ++i) {
        int slot = wid * 4 + i;
        *(bf16x8*)&Kt[p ^ 1][slot * 512 + lane * 8] = kst[i];
        *(bf16x8*)&Vt[p ^ 1][wid * 2048 + i * 512 + lane * 8] = vst[i];
      }
    }
    __syncthreads();
  }

  float* Opb = (s ? Op1 : Op0) + (size_t)b * NPIX * CC;
  #pragma unroll
  for (int cf = 0; cf < 16; ++cf)
    #pragma unroll
    for (int r = 0; r < 4; ++r)
      Opb[(size_t)(q0 + wid * 16 + g4 * 4 + r) * CC + cf * 16 + r16] = O[cf][r];
  if (r16 == 0) {
    #pragma unroll
    for (int r = 0; r < 4; ++r)
      ml2[(size_t)(s * BB + b) * NPIX + q0 + wid * 16 + g4 * 4 + r] =
          make_float2(mrow[r], lrow[r]);
  }
}

// ---------------- combine the 2 K-split attn partials -> y bf16 [B,N,C] ----------------
__global__ void attn_combine_k(const float* __restrict__ Op0, const float* __restrict__ Op1,
                               const float2* __restrict__ ml2, unsigned short* __restrict__ y) {
  size_t e = ((size_t)blockIdx.x * 256 + threadIdx.x) * 8;
  int bn = (int)(e >> 8);
  float2 a = ml2[bn];
  float2 c = ml2[16384 + bn];
  float M = fmaxf(a.x, c.x);
  float e0 = __expf(a.x - M), e1 = __expf(c.x - M);
  float L = a.y * e0 + c.y * e1;
  float sc = L > 1e-30f ? 1.f / L : 0.f;
  e0 *= sc; e1 *= sc;
  f32x4 p0 = *(const f32x4*)&Op0[e];
  f32x4 p1 = *(const f32x4*)&Op0[e + 4];
  f32x4 q0 = *(const f32x4*)&Op1[e];
  f32x4 q1 = *(const f32x4*)&Op1[e + 4];
  bf16x8 r;
  #pragma unroll
  for (int j = 0; j < 4; ++j) {
    r[j]     = (short)f2b(p0[j] * e0 + q0[j] * e1);
    r[4 + j] = (short)f2b(p1[j] * e0 + q1[j] * e1);
  }
  *(bf16x8*)&y[e] = r;
}

__global__ void in_finalize_k(const float* __restrict__ psum, const float* __restrict__ psumsq,
                              float* __restrict__ mu, float* __restrict__ rs) {
  int bc = blockIdx.x * 256 + threadIdx.x;
  int b = bc >> 8, c = bc & 255;
  float s = 0.f, s2 = 0.f;
  for (int p = 0; p < 32; ++p) {
    s  += psum[(p * BB + b) * CC + c];
    s2 += psumsq[(p * BB + b) * CC + c];
  }
  float m_ = s * (1.f / 4096.f);
  float var = s2 * (1.f / 4096.f) - m_ * m_;
  var = var > 0.f ? var : 0.f;
  mu[bc] = m_;
  rs[bc] = rsqrtf(var + 1e-5f);
}

// ---------------- IN+ReLU apply ----------------
__global__ void normrelu_k(const unsigned short* __restrict__ src,
                           const float* __restrict__ mu, const float* __restrict__ rs,
                           unsigned short* __restrict__ dst) {
  size_t idx = (size_t)blockIdx.x * 256 + threadIdx.x;
  size_t e = idx * 8;
  if (e >= (size_t)BB * PB) return;
  int c = (int)(e & 255);
  int b = (int)(e >> 20);
  const float* mup = mu + b * 256 + c;
  const float* rsp = rs + b * 256 + c;
  bf16x8 v = *(const bf16x8*)(src + e);
  bf16x8 ov;
  #pragma unroll
  for (int j = 0; j < 8; ++j) {
    float f = (b2f((unsigned short)v[j]) - mup[j]) * rsp[j];
    ov[j] = (short)f2b(f > 0.f ? f : 0.f);
  }
  *(bf16x8*)(dst + e) = ov;
}

// ---------------- residual += IN(conv2), keep f32 + bf16 ----------------
__global__ void resupdate_k(const unsigned short* __restrict__ c2,
                            const float* __restrict__ mu, const float* __restrict__ rs,
                            float* __restrict__ r, unsigned short* __restrict__ rb) {
  size_t idx = (size_t)blockIdx.x * 256 + threadIdx.x;
  size_t e = idx * 8;
  if (e >= (size_t)BB * PB) return;
  int c = (int)(e & 255);
  int b = (int)(e >> 20);
  const float* mup = mu + b * 256 + c;
  const float* rsp = rs + b * 256 + c;
  bf16x8 v = *(const bf16x8*)(c2 + e);
  bf16x8 ov;
  #pragma unroll
  for (int j = 0; j < 8; ++j) {
    float f = r[e + j] + (b2f((unsigned short)v[j]) - mup[j]) * rsp[j];
    r[e + j] = f;
    ov[j] = (short)f2b(f);
  }
  *(bf16x8*)(rb + e) = ov;
}

// ---------------- final blend ----------------
__global__ void final_blend_k(const float* __restrict__ x, const float* __restrict__ r,
                              const float* __restrict__ m, float* __restrict__ out) {
  __shared__ float T[64][65];
  int b = blockIdx.z;
  int n0 = blockIdx.x * 64, c0 = blockIdx.y * 64;
  int tx = threadIdx.x, ty = threadIdx.y;
  #pragma unroll
  for (int i = 0; i < 16; ++i) {
    int nl = ty + i * 4;
    T[nl][tx] = r[(size_t)b * PB + (size_t)(n0 + nl) * CC + c0 + tx];
  }
  __syncthreads();
  #pragma unroll
  for (int i = 0; i < 16; ++i) {
    int cl = ty + i * 4;
    int cg = c0 + cl, ng = n0 + tx;
    float mv = m[b * NPIX + ng];
    float xv = x[(size_t)b * PB + (size_t)cg * NPIX + ng];
    out[(size_t)b * PB + (size_t)cg * NPIX + ng] = mv * xv + (1.f - mv) * T[tx][cl];
  }
}

// ---------------- workspace layout (bytes) ----------------
#define OFF_M    0UL            // mask f32 [B,N] 64KB
#define OFF_XT   65536UL        // 8MB: xT -> phic (gather) -> ybuf (combine)
#define OFF_TH   8454144UL      // 8MB: theta [B,N,C] -> cbuf
#define OFF_PH   16842752UL     // 8MB: phi [B,N,C] -> gc -> hbuf
#define OFF_G    25231360UL     // 8MB: g [C,NTOT] -> rb
#define OFF_R    33619968UL     // 16MB: attn op0 -> rbuf f32 [B,N,C]
#define OFF_W1   50397184UL     // 1x1 weights bf16 stacked: theta|phi|g|W
#define OFF_WK   50921472UL     // res conv weights bf16 [6][9][256][256]
#define OFF_MU   57999360UL
#define OFF_RS   58003456UL
#define OFF_PS   58007552UL
#define OFF_PS2  58138624UL
#define OFF_OP1  58269696UL     // attn partial split1 f32; later conv partial split0 (16MB)
#define OFF_ML   75046912UL     // (m,l) float2 [2][B][N] (256KB)
#define OFF_CI   75309056UL     // compact indices int [B][4096] (64KB)
#define OFF_KC   75374592UL     // kcount int[4]
#define OFF_BIAS 75374848UL     // stacked bias f32 [1024]

extern "C" void kernel_launch(void* const* d_in, const int* in_sizes, int n_in,
                              void* d_out, int out_size, void* d_ws, size_t ws_size,
                              hipStream_t stream) {
  const float* x       = (const float*)d_in[0];
  const float* maskp   = (const float*)d_in[1];
  const float* g_w     = (const float*)d_in[2];
  const float* g_b     = (const float*)d_in[3];
  const float* theta_w = (const float*)d_in[4];
  const float* theta_b = (const float*)d_in[5];
  const float* phi_w   = (const float*)d_in[6];
  const float* phi_b   = (const float*)d_in[7];
  const float* W_w     = (const float*)d_in[8];
  const float* W_b     = (const float*)d_in[9];
  const float* res_w1  = (const float*)d_in[10];
  const float* res_w2  = (const float*)d_in[12];
  float* out = (float*)d_out;
  char* ws = (char*)d_ws;

  float*          mbuf = (float*)(ws + OFF_M);
  unsigned short* xT   = (unsigned short*)(ws + OFF_XT);
  unsigned short* phic = (unsigned short*)(ws + OFF_XT);   // alias
  unsigned short* ybuf = (unsigned short*)(ws + OFF_XT);   // alias
  unsigned short* thb  = (unsigned short*)(ws + OFF_TH);
  unsigned short* cbuf = (unsigned short*)(ws + OFF_TH);   // alias
  unsigned short* phb  = (unsigned short*)(ws + OFF_PH);
  unsigned short* gc   = (unsigned short*)(ws + OFF_PH);   // alias
  unsigned short* hbuf = (unsigned short*)(ws + OFF_PH);   // alias
  unsigned short* gbuf = (unsigned short*)(ws + OFF_G);
  unsigned short* rb   = (unsigned short*)(ws + OFF_G);    // alias
  float*          rbuf = (float*)(ws + OFF_R);
  float*          aop0 = (float*)(ws + OFF_R);             // attn partial 0 (alias rbuf)
  float*          aop1 = (float*)(ws + OFF_OP1);           // attn partial 1
  float*          cp0  = (float*)(ws + OFF_OP1);           // conv partial split0 (reuse)
  float*          cp1  = out;                              // conv partial split1 = d_out scratch
  float2*         ml2  = (float2*)(ws + OFF_ML);
  int*            ci   = (int*)(ws + OFF_CI);
  int*            kc   = (int*)(ws + OFF_KC);
  float*          biasS= (float*)(ws + OFF_BIAS);
  unsigned short* thw  = (unsigned short*)(ws + OFF_W1);   // stacked theta|phi|g|W
  unsigned short* Www  = (unsigned short*)(ws + OFF_W1 + 393216);
  unsigned short* wkres= (unsigned short*)(ws + OFF_WK);
  float*          mu   = (float*)(ws + OFF_MU);
  float*          rs   = (float*)(ws + OFF_RS);
  float*          psum = (float*)(ws + OFF_PS);
  float*          psq  = (float*)(ws + OFF_PS2);

  // prep
  repack_w1x1_k<<<256, 256, 0, stream>>>(theta_w, phi_w, g_w, W_w, thw);
  repack_res_k<<<6912, 256, 0, stream>>>(res_w1, res_w2, wkres);
  repack_bias_k<<<4, 256, 0, stream>>>(theta_b, phi_b, g_b, W_b, biasS);
  prep_mask_k<<<64, 256, 0, stream>>>(maskp, mbuf);
  transpose_x_k<<<dim3(64, 4, 4), dim3(64, 4), 0, stream>>>(x, xT);

  // fused theta|phi|g projection (M=768) -- 768 blocks = 3/CU
  gemm_w<0, 1, 1><<<dim3(128, 6), 256, 0, stream>>>(thw, xT, biasS, nullptr, thb, phb, gbuf);

  // key compaction
  mask_scan_k<<<4, 256, 0, stream>>>(mbuf, ci, kc);
  gather_phi_k<<<dim3(512, 4), 256, 0, stream>>>(phb, ci, kc, phic);
  gather_g_k<<<dim3(16, 256, 4), 256, 0, stream>>>(gbuf, ci, kc, gc);

  // flash attention over compacted keys (K-split 2) + combine
  attn_k<<<256, 512, 0, stream>>>(thb, phic, gc, kc, aop0, aop1, ml2);
  attn_combine_k<<<2048, 256, 0, stream>>>(aop0, aop1, ml2, ybuf);

  // W_y projection -> residual f32 + bf16
  gemm_w<2, 1, 1><<<dim3(128, 2), 256, 0, stream>>>(Www, ybuf, biasS + 768, rbuf, rb,
                                                    nullptr, nullptr);

  // 3 residual blocks: K-split conv (f32 partials) -> combine+stats -> finalize -> apply
  for (int i = 0; i < 3; ++i) {
    gemm_w<3, 9, 2><<<dim3(128, 2, 2), 256, 0, stream>>>(
        wkres + (size_t)(2 * i) * 589824, rb, nullptr, cp0,
        (unsigned short*)cp1, nullptr, nullptr);
    combine_stats_k<<<dim3(32, 4), 256, 0, stream>>>(cp0, cp1, cbuf, psum, psq);
    in_finalize_k<<<4, 256, 0, stream>>>(psum, psq, mu, rs);
    normrelu_k<<<2048, 256, 0, stream>>>(cbuf, mu, rs, hbuf);
    gemm_w<3, 9, 2><<<dim3(128, 2, 2), 256, 0, stream>>>(
        wkres + (size_t)(2 * i + 1) * 589824, hbuf, nullptr, cp0,
        (unsigned short*)cp1, nullptr, nullptr);
    combine_stats_k<<<dim3(32, 4), 256, 0, stream>>>(cp0, cp1, cbuf, psum, psq);
    in_finalize_k<<<4, 256, 0, stream>>>(psum, psq, mu, rs);
    resupdate_k<<<2048, 256, 0, stream>>>(cbuf, mu, rs, rbuf, rb);
  }

  // final blend + transpose to [B,C,H,W] (overwrites d_out scratch)
  final_blend_k<<<dim3(64, 4, 4), dim3(64, 4), 0, stream>>>(x, rbuf, mbuf, out);
}